// Round 6
// baseline (226.499 us; speedup 1.0000x reference)
//
#include <hip/hip_runtime.h>
#include <stdint.h>

#define BDIM    512                   // 8 waves per batch
#define NROWS   32
#define CDIM    1024
#define NSTEPS  31
#define BATCH   512

// One 512-thread block (8 waves) per batch. ALL alive rows live in REGISTERS:
// wave w owns 4 "banks" k=0..3 holding slots s = w + 8k (strided ownership,
// balanced init); lane holds elements [lane*16..+15]. Merged row overwrites
// slot sb's bank and D-row. The OTHER dead slot is idx[a] normally but
// idx[0] when a==1 (reference quirk) — kill THAT bank.
//
// 2 BARRIERS/STEP. B3 removed via merged-row side channel: phase B's lanes
// 0-3 hold the fresh d2(merged,live) values in registers; they write keys
// (d2_bits<<10)|flat' into wp[8..15] (flat' = partner's NEXT-step position,
// = 0*n'+j' — provably smaller than any old-pair flat => exact reference
// tie order). Next step's scan EXCLUDES slot sbPrev (the only D cells
// written concurrently) and the post-B1 reduce covers all 16 partials.
// Position maps are double-buffered (posbuf[2]); every cross-wave dependency
// crosses >=1 barrier; the barrier-free phase-B->scan window touches
// disjoint LDS addresses only.
//
// ALL distance math fp32 (validated: decisions identical, margins >> fp32
// noise). Argmin key u64 = (float_bits(d2)<<10)|flat, branch-free min.
// conv partials float4-packed, lane-aligned (4x ds_read_b128 per array).
// No global reads after init.
__device__ __forceinline__ float reduce4f(float a0, float a1, float a2, float a3, int lane) {
    // Joint wave-sum of 4 fp32 values; lane l ends holding S_{l&3}.
    float t, r, b01, b23, c;
    t = (lane & 1) ? a0 : a1; r = (lane & 1) ? a1 : a0; b01 = r + __shfl_xor(t, 1);
    t = (lane & 1) ? a2 : a3; r = (lane & 1) ? a3 : a2; b23 = r + __shfl_xor(t, 1);
    t = (lane & 2) ? b01 : b23; r = (lane & 2) ? b23 : b01; c = r + __shfl_xor(t, 2);
    c += __shfl_xor(c, 4); c += __shfl_xor(c, 8); c += __shfl_xor(c, 16); c += __shfl_xor(c, 32);
    return c;
}

__global__ __launch_bounds__(BDIM, 4)
void merge_tree_kernel(const float* __restrict__ xin,  // B*32*1024 fp32
                       const float* __restrict__ wz,   // 6 fp32 (1,2,3)
                       const float* __restrict__ bz,   // 1 fp32
                       float* __restrict__ out)        // B*1024 fp32
{
    const int b    = blockIdx.x;
    const int tid  = threadIdx.x;
    const int lane = tid & 63;
    const int wid  = tid >> 6;        // 0..7

    const float* xb = xin + (size_t)b * NROWS * CDIM;

    __shared__ float  D[NROWS][NROWS + 1];   // slot-indexed d2, fp32, padded
    __shared__ float4 mA4[4 * 64];           // conv partial (ch0), [q][lane] float4
    __shared__ float4 mB4[4 * 64];           // conv partial (ch1), [q][lane] float4
    __shared__ int    idxbuf[2][NROWS];      // logical pos -> slot (dbl-buffered)
    __shared__ int    posbuf[2][NROWS];      // slot -> logical pos, 127 = dead
    __shared__ int    bankSlot[32];          // bank (wid*4+k) -> slot, -1 dead
    __shared__ unsigned long long wp[16];    // argmin partials: [0..7] scan, [8..15] merged-row

    const float w00 = wz[0], w01 = wz[1], w02 = wz[2];
    const float w10 = wz[3], w11 = wz[4], w12 = wz[5];
    const float cb  = bz[0];

    float R[4][16];                   // 4 owned rows (64 VGPRs)
    float m[16];                      // streamed / merged row
    float nxt[16];                    // init prefetch buffer

    if (tid < NROWS) {
        idxbuf[0][tid] = tid;
        posbuf[0][tid] = tid;
        bankSlot[tid] = (tid >> 2) + ((tid & 3) << 3);   // strided ownership
    }
    if (tid < 16) wp[tid] = ~0ull;    // wp[8..15] must be empty for step 0

    // ---------- single-pass init: stream row i, owner captures, dist vs s<i ----------
    {
        const float4* src = (const float4*)xb;    // row 0
        #pragma unroll
        for (int q = 0; q < 4; q++) {
            float4 t = src[lane * 4 + q];
            m[4*q] = t.x; m[4*q+1] = t.y; m[4*q+2] = t.z; m[4*q+3] = t.w;
        }
    }
    #pragma unroll 1
    for (int i = 0; i < NROWS; i++) {
        if (i < NROWS - 1) {                      // prefetch row i+1
            const float4* src = (const float4*)(xb + (size_t)(i + 1) * CDIM);
            #pragma unroll
            for (int q = 0; q < 4; q++) {
                float4 t = src[lane * 4 + q];
                nxt[4*q] = t.x; nxt[4*q+1] = t.y; nxt[4*q+2] = t.z; nxt[4*q+3] = t.w;
            }
        }
        float accv[4];
        #pragma unroll
        for (int k = 0; k < 4; k++) {
            const int s = wid + (k << 3);         // strided slot, wave-uniform
            float acc0 = 0.0f, acc1 = 0.0f;
            if (s < i) {                          // wave-uniform
                #pragma unroll
                for (int e = 0; e < 8; e++) {
                    float d0 = m[e] - R[k][e];
                    float d1 = m[e + 8] - R[k][e + 8];
                    acc0 += d0 * d0;
                    acc1 += d1 * d1;
                }
            } else if (s == i) {                  // owner captures streamed row
                #pragma unroll
                for (int e = 0; e < 16; e++) R[k][e] = m[e];
            }
            accv[k] = acc0 + acc1;
        }
        float c = reduce4f(accv[0], accv[1], accv[2], accv[3], lane);
        int s_lane = wid + ((lane & 3) << 3);     // slot for this lane's sum
        if (lane < 4 && s_lane < i) { D[i][s_lane] = c; D[s_lane][i] = c; }

        if (i < NROWS - 1) {
            #pragma unroll
            for (int e = 0; e < 16; e++) m[e] = nxt[e];
        }
    }
    __syncthreads();

    // ---------- main merge loop: 2 barriers/step ----------
    int p = 0;
    int sbPrev = 127;                 // step 0: exclude nothing
    #pragma unroll 1
    for (int step = 0; step < NSTEPS; step++) {
        const int n = NROWS - step;
        int* idx  = idxbuf[p];
        int* nidx = idxbuf[p ^ 1];
        int* pos  = posbuf[p];
        int* npos = posbuf[p ^ 1];
        const uint32_t M = 0xFFFFFFFFu / (uint32_t)n + 1u;  // exact for flat<2^27

        // --- scan OLD-OLD pairs (exclude sbPrev: those cells may still be
        //     in flight from the previous phase B; their mins are wp[8..15]) ---
        unsigned long long bk = ~0ull;
        #pragma unroll
        for (int r = 0; r < (NROWS * NROWS) / BDIM; r++) {  // 2 iterations
            const int flat = r * BDIM + tid;
            const int s = flat >> 5, t = flat & 31;
            const int li = pos[s], lj = pos[t];             // independent LDS loads
            if (t > s && li < n && lj < n && s != sbPrev && t != sbPrev) {
                uint32_t d2b = __float_as_uint(D[s][t]);    // d2 >= 0: monotone bits
                int i2 = (li < lj) ? li : lj;
                int j2 = (li < lj) ? lj : li;
                unsigned long long key =
                    ((unsigned long long)d2b << 10) | (unsigned)(i2 * n + j2);
                bk = (key < bk) ? key : bk;
            }
        }
        #pragma unroll
        for (int off = 1; off < 64; off <<= 1) {
            unsigned long long ov = __shfl_xor(bk, off);
            bk = (ov < bk) ? ov : bk;
        }
        if (lane == 0) wp[wid] = bk;
        __syncthreads();                                   // B1

        // --- final reduce of 16 partials, redundant on every thread ---
        bk = wp[0];
        #pragma unroll
        for (int w = 1; w < 16; w++) {
            unsigned long long ov = wp[w];
            bk = (ov < bk) ? ov : bk;
        }
        const int bp  = (int)(bk & 1023u);
        const int a   = (int)__umulhi((uint32_t)bp, M);
        const int bbj = bp - a * n;
        const int sa  = idx[a], sb = idx[bbj];
        const int deadSlot = (a == 1) ? idx[0] : sa;

        // --- conv partials by owner waves, from registers, float4-packed LDS ---
        #pragma unroll
        for (int k = 0; k < 4; k++) {
            const int s = bankSlot[wid * 4 + k];           // own entry, wave-uniform
            if (s == sa || s == sb) {
                float hl = __shfl_up(R[k][15], 1);  if (lane == 0)  hl = 0.0f;
                float hr = __shfl_down(R[k][0], 1); if (lane == 63) hr = 0.0f;
                float4* dst = (s == sa) ? mA4 : mB4;
                const float c0 = (s == sa) ? w00 : w10;
                const float c1 = (s == sa) ? w01 : w11;
                const float c2 = (s == sa) ? w02 : w12;
                #pragma unroll
                for (int q = 0; q < 4; q++) {
                    float vv[4];
                    #pragma unroll
                    for (int j = 0; j < 4; j++) {
                        const int e = 4 * q + j;
                        float xm1 = (e == 0)  ? hl : R[k][e - 1];
                        float xp1 = (e == 15) ? hr : R[k][e + 1];
                        vv[j] = c0 * xm1 + c1 * R[k][e] + c2 * xp1;
                    }
                    dst[q * 64 + lane] = make_float4(vv[0], vv[1], vv[2], vv[3]);
                }
            }
        }
        // --- bookkeeping into NEXT buffers (old buffers stay read-only) ---
        if (tid == 0) nidx[0] = sb;
        if (tid >= 1 && tid < n - 1) {
            int kk = tid + 1;
            int src = (kk == bbj) ? 1 : ((kk == a) ? 0 : kk);
            nidx[tid] = idx[src];
        }
        if (tid < NROWS) {                                 // slot -> next-step pos
            const int oldp = pos[tid];
            int np;
            if (tid == sb)            np = 0;              // merged row
            else if (tid == deadSlot) np = 127;            // dies this step
            else if (oldp >= n)       np = 127;            // already dead
            else if (oldp == 0)       np = a - 1;          // only reached when a>=2
            else if (oldp == 1)       np = bbj - 1;        // only reached when bbj>=2
            else                      np = oldp - 1;
            npos[tid] = np;
        }
        __syncthreads();                                   // B2

        // --- finalize m: 4x ds_read_b128 per array, conflict-free ---
        #pragma unroll
        for (int q = 0; q < 4; q++) {
            float4 va = mA4[q * 64 + lane];
            float4 vb = mB4[q * 64 + lane];
            float v0 = cb + va.x + vb.x;
            float v1 = cb + va.y + vb.y;
            float v2 = cb + va.z + vb.z;
            float v3 = cb + va.w + vb.w;
            m[4*q+0] = v0 > 0.0f ? v0 : 0.0f;
            m[4*q+1] = v1 > 0.0f ? v1 : 0.0f;
            m[4*q+2] = v2 > 0.0f ? v2 : 0.0f;
            m[4*q+3] = v3 > 0.0f ? v3 : 0.0f;
        }
        // owner(sb): bank <- m; owner(deadSlot): kill bank; dists vs live banks
        float accv[4]; int slv[4];
        #pragma unroll
        for (int k = 0; k < 4; k++) {
            int s = bankSlot[wid * 4 + k];
            if (s == sb) {                                 // wave-uniform
                #pragma unroll
                for (int e = 0; e < 16; e++) R[k][e] = m[e];
            }
            if (s == deadSlot) {
                if (lane == 0) bankSlot[wid * 4 + k] = -1;
                s = -1;
            }
            const int live = (s >= 0 && s != sb) ? s : -1;
            slv[k] = live;
            float acc0 = 0.0f, acc1 = 0.0f;
            if (live >= 0) {                               // wave-uniform
                #pragma unroll
                for (int e = 0; e < 8; e++) {
                    float d0 = m[e] - R[k][e];
                    float d1 = m[e + 8] - R[k][e + 8];
                    acc0 += d0 * d0;
                    acc1 += d1 * d1;
                }
            }
            accv[k] = acc0 + acc1;
        }
        // joint reduce: lane l holds sum for bank (l&3)
        float c = reduce4f(accv[0], accv[1], accv[2], accv[3], lane);
        int s_lane = slv[0];
        s_lane = ((lane & 3) == 1) ? slv[1] : s_lane;
        s_lane = ((lane & 3) == 2) ? slv[2] : s_lane;
        s_lane = ((lane & 3) == 3) ? slv[3] : s_lane;
        // write D + side-channel key for next step's argmin (flat' = 0*n'+j')
        unsigned long long nk = ~0ull;
        if (lane < 4 && s_lane >= 0) {
            D[sb][s_lane] = c; D[s_lane][sb] = c;
            const int fl = npos[s_lane];                   // partner next-step pos >= 1
            nk = ((unsigned long long)__float_as_uint(c) << 10) | (unsigned)fl;
        }
        {   // mini-reduce over lanes 0..3 (closed under xor 1,2)
            unsigned long long ov = __shfl_xor(nk, 1); nk = (ov < nk) ? ov : nk;
            ov = __shfl_xor(nk, 2);                    nk = (ov < nk) ? ov : nk;
        }
        if (lane == 0) wp[8 + wid] = nk;
        sbPrev = sb;
        p ^= 1;
        // NO third barrier: next scan excludes slot sbPrev (the only cells
        // written here); wp[8..15] reads are after next step's B1.
    }

    // final merged row is in m (all waves); wave 0 writes it
    if (wid == 0) {
        float4* od = (float4*)(out + (size_t)b * CDIM);
        #pragma unroll
        for (int q = 0; q < 4; q++)
            od[lane * 4 + q] = make_float4(m[4*q], m[4*q+1], m[4*q+2], m[4*q+3]);
    }
}

extern "C" void kernel_launch(void* const* d_in, const int* in_sizes, int n_in,
                              void* d_out, int out_size, void* d_ws, size_t ws_size,
                              hipStream_t stream) {
    const float* x  = (const float*)d_in[0]; // fp32 (512,32,1024)
    const float* w  = (const float*)d_in[1]; // fp32 (1,2,3)
    const float* cb = (const float*)d_in[2]; // fp32 (1,)
    float* out = (float*)d_out;              // fp32 (512,1024)
    (void)d_ws; (void)ws_size; (void)in_sizes; (void)n_in; (void)out_size;

    hipLaunchKernelGGL(merge_tree_kernel, dim3(BATCH), dim3(BDIM), 0, stream,
                       x, w, cb, out);
}

// Round 7
// 226.335 us; speedup vs baseline: 1.0007x; 1.0007x over previous
//
#include <hip/hip_runtime.h>
#include <stdint.h>

#define BDIM    1024                  // 2 batch-halves x 8 waves
#define NROWS   32
#define CDIM    1024
#define NSTEPS  31
#define BATCH   512

// TWO independent batches per 1024-thread block (half = tid>>9), each half
// an 8-wave group with the round-5 structure. Doubles resident waves/CU
// (16 -> 32): 4 independent merge chains per CU fill each other's
// dependent-shuffle/barrier stalls. All step loops are compile-time bound,
// so both halves reach every __syncthreads together; barriers sync both
// halves (slight skew cost << stall-filling gain).
//
// Per half: ALL alive rows in REGISTERS: wave w owns banks k=0..3 holding
// slots s = w + 8k (strided, balanced init); lane holds elements
// [lane*16..+15]. Merged row overwrites slot sb's bank and D-row. The OTHER
// dead slot is idx[a] normally but idx[0] when a==1 (reference quirk).
//
// ALL distance math fp32 (validated: decisions identical, margins >> fp32
// noise; absmax bit-identical across fp64->fp32 switch). Argmin key
// u64 = (float_bits(d2)<<10)|flat — float bits order-monotone for d2>=0,
// flat<1024; u64 min == reference (d2, flat) lexicographic order.
// conv partials float4-packed, lane-aligned (4x ds_read_b128 per array).
// 3 barriers/step. No global reads after init.
__device__ __forceinline__ float reduce4f(float a0, float a1, float a2, float a3, int lane) {
    // Joint wave-sum of 4 fp32 values; lane l ends holding S_{l&3}.
    float t, r, b01, b23, c;
    t = (lane & 1) ? a0 : a1; r = (lane & 1) ? a1 : a0; b01 = r + __shfl_xor(t, 1);
    t = (lane & 1) ? a2 : a3; r = (lane & 1) ? a3 : a2; b23 = r + __shfl_xor(t, 1);
    t = (lane & 2) ? b01 : b23; r = (lane & 2) ? b23 : b01; c = r + __shfl_xor(t, 2);
    c += __shfl_xor(c, 4); c += __shfl_xor(c, 8); c += __shfl_xor(c, 16); c += __shfl_xor(c, 32);
    return c;
}

__global__ __launch_bounds__(BDIM, 4)
void merge_tree_kernel(const float* __restrict__ xin,  // B*32*1024 fp32
                       const float* __restrict__ wz,   // 6 fp32 (1,2,3)
                       const float* __restrict__ bz,   // 1 fp32
                       float* __restrict__ out)        // B*1024 fp32
{
    const int tid0 = threadIdx.x;
    const int half = tid0 >> 9;       // 0..1: which batch of this block
    const int tid  = tid0 & 511;      // local tid within the half
    const int lane = tid & 63;
    const int wid  = tid >> 6;        // 0..7 within the half
    const int b    = blockIdx.x * 2 + half;

    const float* xb = xin + (size_t)b * NROWS * CDIM;

    __shared__ float  Ds[2][NROWS][NROWS + 1];  // slot-indexed d2, fp32, padded
    __shared__ float4 mA4s[2][4 * 64];          // conv partial (ch0), [q][lane]
    __shared__ float4 mB4s[2][4 * 64];          // conv partial (ch1), [q][lane]
    __shared__ int    idxbufs[2][2][NROWS];     // logical pos -> slot
    __shared__ int    posbs[2][NROWS];          // slot -> logical pos, 127 = dead
    __shared__ int    bankSlots[2][32];         // bank (wid*4+k) -> slot, -1 dead
    __shared__ unsigned long long wps[2][8];    // per-wave argmin partial key

    float (*D)[NROWS + 1] = Ds[half];
    float4* mA4 = mA4s[half];
    float4* mB4 = mB4s[half];
    int (*idxbuf)[NROWS] = idxbufs[half];
    int* posb = posbs[half];
    int* bankSlot = bankSlots[half];
    unsigned long long* wp = wps[half];

    const float w00 = wz[0], w01 = wz[1], w02 = wz[2];
    const float w10 = wz[3], w11 = wz[4], w12 = wz[5];
    const float cb  = bz[0];

    float R[4][16];                   // 4 owned rows (64 VGPRs)
    float m[16];                      // streamed / merged row
    float nxt[16];                    // init prefetch buffer

    if (tid < NROWS) {
        idxbuf[0][tid] = tid;
        posb[tid] = tid;
        bankSlot[tid] = (tid >> 2) + ((tid & 3) << 3);   // strided ownership
    }

    // ---------- single-pass init: stream row i, owner captures, dist vs s<i ----------
    {
        const float4* src = (const float4*)xb;    // row 0
        #pragma unroll
        for (int q = 0; q < 4; q++) {
            float4 t = src[lane * 4 + q];
            m[4*q] = t.x; m[4*q+1] = t.y; m[4*q+2] = t.z; m[4*q+3] = t.w;
        }
    }
    #pragma unroll 1
    for (int i = 0; i < NROWS; i++) {
        if (i < NROWS - 1) {                      // prefetch row i+1
            const float4* src = (const float4*)(xb + (size_t)(i + 1) * CDIM);
            #pragma unroll
            for (int q = 0; q < 4; q++) {
                float4 t = src[lane * 4 + q];
                nxt[4*q] = t.x; nxt[4*q+1] = t.y; nxt[4*q+2] = t.z; nxt[4*q+3] = t.w;
            }
        }
        float accv[4];
        #pragma unroll
        for (int k = 0; k < 4; k++) {
            const int s = wid + (k << 3);         // strided slot, wave-uniform
            float acc0 = 0.0f, acc1 = 0.0f;
            if (s < i) {                          // wave-uniform
                #pragma unroll
                for (int e = 0; e < 8; e++) {
                    float d0 = m[e] - R[k][e];
                    float d1 = m[e + 8] - R[k][e + 8];
                    acc0 += d0 * d0;
                    acc1 += d1 * d1;
                }
            } else if (s == i) {                  // owner captures streamed row
                #pragma unroll
                for (int e = 0; e < 16; e++) R[k][e] = m[e];
            }
            accv[k] = acc0 + acc1;
        }
        float c = reduce4f(accv[0], accv[1], accv[2], accv[3], lane);
        int s_lane = wid + ((lane & 3) << 3);     // slot for this lane's sum
        if (lane < 4 && s_lane < i) { D[i][s_lane] = c; D[s_lane][i] = c; }

        if (i < NROWS - 1) {
            #pragma unroll
            for (int e = 0; e < 16; e++) m[e] = nxt[e];
        }
    }
    __syncthreads();

    // ---------- main merge loop: 3 barriers/step ----------
    int p = 0;
    #pragma unroll 1
    for (int step = 0; step < NSTEPS; step++) {
        const int n = NROWS - step;
        int* idx  = idxbuf[p];
        int* nidx = idxbuf[p ^ 1];
        const uint32_t M = 0xFFFFFFFFu / (uint32_t)n + 1u;  // exact for flat<2^27

        // --- parallel argmin over slot pairs, all 512 half-threads, u64 keys ---
        unsigned long long bk = ~0ull;
        #pragma unroll
        for (int r = 0; r < 2; r++) {                       // 1024 pairs / 512 threads
            const int flat = r * 512 + tid;
            const int s = flat >> 5, t = flat & 31;
            const int li = posb[s], lj = posb[t];           // independent LDS loads
            if (t > s && li < n && lj < n) {                // live pair, once
                uint32_t d2b = __float_as_uint(D[s][t]);    // d2 >= 0: monotone bits
                int i2 = (li < lj) ? li : lj;
                int j2 = (li < lj) ? lj : li;
                unsigned long long key =
                    ((unsigned long long)d2b << 10) | (unsigned)(i2 * n + j2);
                bk = (key < bk) ? key : bk;
            }
        }
        #pragma unroll
        for (int off = 1; off < 64; off <<= 1) {
            unsigned long long ov = __shfl_xor(bk, off);
            bk = (ov < bk) ? ov : bk;
        }
        if (lane == 0) wp[wid] = bk;
        __syncthreads();                                   // B1

        // --- final reduce of 8 partials, redundant on every thread (uniform) ---
        bk = wp[0];
        #pragma unroll
        for (int w = 1; w < 8; w++) {
            unsigned long long ov = wp[w];
            bk = (ov < bk) ? ov : bk;
        }
        const int bp  = (int)(bk & 1023u);
        const int a   = (int)__umulhi((uint32_t)bp, M);
        const int bbj = bp - a * n;
        const int sa  = idx[a], sb = idx[bbj];
        const int deadSlot = (a == 1) ? idx[0] : sa;

        // --- conv partials by owner waves, from registers, float4-packed LDS ---
        #pragma unroll
        for (int k = 0; k < 4; k++) {
            const int s = bankSlot[wid * 4 + k];           // own entry, wave-uniform
            if (s == sa || s == sb) {
                float hl = __shfl_up(R[k][15], 1);  if (lane == 0)  hl = 0.0f;
                float hr = __shfl_down(R[k][0], 1); if (lane == 63) hr = 0.0f;
                float4* dst = (s == sa) ? mA4 : mB4;
                const float c0 = (s == sa) ? w00 : w10;
                const float c1 = (s == sa) ? w01 : w11;
                const float c2 = (s == sa) ? w02 : w12;
                #pragma unroll
                for (int q = 0; q < 4; q++) {
                    float vv[4];
                    #pragma unroll
                    for (int j = 0; j < 4; j++) {
                        const int e = 4 * q + j;
                        float xm1 = (e == 0)  ? hl : R[k][e - 1];
                        float xp1 = (e == 15) ? hr : R[k][e + 1];
                        vv[j] = c0 * xm1 + c1 * R[k][e] + c2 * xp1;
                    }
                    dst[q * 64 + lane] = make_float4(vv[0], vv[1], vv[2], vv[3]);
                }
            }
        }
        // --- bookkeeping: next logical order + slot->pos (all distinct slots) ---
        if (tid == 0) { nidx[0] = sb; posb[sb] = 0; posb[deadSlot] = 127; }
        if (tid >= 1 && tid < n - 1) {
            int kk = tid + 1;
            int src = (kk == bbj) ? 1 : ((kk == a) ? 0 : kk);
            int sl2 = idx[src];
            nidx[tid] = sl2;
            posb[sl2] = tid;                               // survivors distinct; no race
        }
        __syncthreads();                                   // B2

        // --- finalize m: 4x ds_read_b128 per array, conflict-free ---
        #pragma unroll
        for (int q = 0; q < 4; q++) {
            float4 va = mA4[q * 64 + lane];
            float4 vb = mB4[q * 64 + lane];
            float v0 = cb + va.x + vb.x;
            float v1 = cb + va.y + vb.y;
            float v2 = cb + va.z + vb.z;
            float v3 = cb + va.w + vb.w;
            m[4*q+0] = v0 > 0.0f ? v0 : 0.0f;
            m[4*q+1] = v1 > 0.0f ? v1 : 0.0f;
            m[4*q+2] = v2 > 0.0f ? v2 : 0.0f;
            m[4*q+3] = v3 > 0.0f ? v3 : 0.0f;
        }
        // owner(sb): bank <- m; owner(deadSlot): kill bank; dists vs live banks
        float accv[4]; int slv[4];
        #pragma unroll
        for (int k = 0; k < 4; k++) {
            int s = bankSlot[wid * 4 + k];
            if (s == sb) {                                 // wave-uniform
                #pragma unroll
                for (int e = 0; e < 16; e++) R[k][e] = m[e];
            }
            if (s == deadSlot) {
                if (lane == 0) bankSlot[wid * 4 + k] = -1;
                s = -1;
            }
            const int live = (s >= 0 && s != sb) ? s : -1;
            slv[k] = live;
            float acc0 = 0.0f, acc1 = 0.0f;
            if (live >= 0) {                               // wave-uniform
                #pragma unroll
                for (int e = 0; e < 8; e++) {
                    float d0 = m[e] - R[k][e];
                    float d1 = m[e + 8] - R[k][e + 8];
                    acc0 += d0 * d0;
                    acc1 += d1 * d1;
                }
            }
            accv[k] = acc0 + acc1;
        }
        // joint reduce: lane l holds sum for bank (l&3)
        float c = reduce4f(accv[0], accv[1], accv[2], accv[3], lane);
        int s_lane = slv[0];
        s_lane = ((lane & 3) == 1) ? slv[1] : s_lane;
        s_lane = ((lane & 3) == 2) ? slv[2] : s_lane;
        s_lane = ((lane & 3) == 3) ? slv[3] : s_lane;
        if (lane < 4 && s_lane >= 0) {
            D[sb][s_lane] = c; D[s_lane][sb] = c;
        }
        __syncthreads();                                   // B3
        p ^= 1;
    }

    // final merged row is in m (all waves of this half); wave 0 writes it
    if (wid == 0) {
        float4* od = (float4*)(out + (size_t)b * CDIM);
        #pragma unroll
        for (int q = 0; q < 4; q++)
            od[lane * 4 + q] = make_float4(m[4*q], m[4*q+1], m[4*q+2], m[4*q+3]);
    }
}

extern "C" void kernel_launch(void* const* d_in, const int* in_sizes, int n_in,
                              void* d_out, int out_size, void* d_ws, size_t ws_size,
                              hipStream_t stream) {
    const float* x  = (const float*)d_in[0]; // fp32 (512,32,1024)
    const float* w  = (const float*)d_in[1]; // fp32 (1,2,3)
    const float* cb = (const float*)d_in[2]; // fp32 (1,)
    float* out = (float*)d_out;              // fp32 (512,1024)
    (void)d_ws; (void)ws_size; (void)in_sizes; (void)n_in; (void)out_size;

    hipLaunchKernelGGL(merge_tree_kernel, dim3(BATCH / 2), dim3(BDIM), 0, stream,
                       x, w, cb, out);
}

// Round 8
// 203.890 us; speedup vs baseline: 1.1109x; 1.1101x over previous
//
#include <hip/hip_runtime.h>
#include <stdint.h>

#define BDIM    512                   // 8 waves per batch
#define NROWS   32
#define CDIM    1024
#define NSTEPS  31
#define BATCH   512

// One 512-thread block (8 waves) per batch. ALL alive rows live in REGISTERS:
// wave w owns 4 "banks" k=0..3 holding slots s = w + 8k (strided ownership,
// balanced init); lane holds elements [lane*16..+15]. Bank->slot map bs[4]
// lives in REGISTERS (only the owning wave ever reads it). Merged row
// overwrites slot sb's bank and D-row. The OTHER dead slot is idx[a]
// normally but idx[0] when a==1 (reference quirk) — kill THAT bank.
//
// Argmin scan in POSITION space via a STATIC 496-entry triangle table
// (pairs i<j<32, filter j<n): exactly one pair per thread, no loop, no
// pos[] array at all. Key u64 = (float_bits(d2)<<10) | (i*n+j) — float
// bits order-monotone for d2>=0; u64 min == reference (d2, flat) order.
// ALL distance math fp32 (validated: decisions identical, margins >> fp32
// noise; absmax bit-identical across fp64->fp32 switch).
// conv partials float4-packed, lane-aligned (4x ds_read_b128 per array).
// 3 barriers/step. No global reads after init.
__device__ __forceinline__ float reduce4f(float a0, float a1, float a2, float a3, int lane) {
    // Joint wave-sum of 4 fp32 values; lane l ends holding S_{l&3}.
    float t, r, b01, b23, c;
    t = (lane & 1) ? a0 : a1; r = (lane & 1) ? a1 : a0; b01 = r + __shfl_xor(t, 1);
    t = (lane & 1) ? a2 : a3; r = (lane & 1) ? a3 : a2; b23 = r + __shfl_xor(t, 1);
    t = (lane & 2) ? b01 : b23; r = (lane & 2) ? b23 : b01; c = r + __shfl_xor(t, 2);
    c += __shfl_xor(c, 4); c += __shfl_xor(c, 8); c += __shfl_xor(c, 16); c += __shfl_xor(c, 32);
    return c;
}

__global__ __launch_bounds__(BDIM, 4)
void merge_tree_kernel(const float* __restrict__ xin,  // B*32*1024 fp32
                       const float* __restrict__ wz,   // 6 fp32 (1,2,3)
                       const float* __restrict__ bz,   // 1 fp32
                       float* __restrict__ out)        // B*1024 fp32
{
    const int b    = blockIdx.x;
    const int tid  = threadIdx.x;
    const int lane = tid & 63;
    const int wid  = tid >> 6;        // 0..7

    const float* xb = xin + (size_t)b * NROWS * CDIM;

    __shared__ float  D[NROWS][NROWS + 1];   // slot-indexed d2, fp32, padded
    __shared__ float4 mA4[4 * 64];           // conv partial (ch0), [q][lane] float4
    __shared__ float4 mB4[4 * 64];           // conv partial (ch1), [q][lane] float4
    __shared__ int    idxbuf[2][NROWS];      // logical pos -> slot (dbl-buffered)
    __shared__ int    pairTab[496];          // static triangle (i<<8)|j, i<j<32
    __shared__ unsigned long long wp[8];     // per-wave argmin partial key

    const float w00 = wz[0], w01 = wz[1], w02 = wz[2];
    const float w10 = wz[3], w11 = wz[4], w12 = wz[5];
    const float cb  = bz[0];

    float R[4][16];                   // 4 owned rows (64 VGPRs)
    float m[16];                      // streamed / merged row
    float nxt[16];                    // init prefetch buffer
    int   bs[4];                      // bank -> slot (own wave only), -1 dead
    #pragma unroll
    for (int k = 0; k < 4; k++) bs[k] = wid + (k << 3);   // strided ownership

    if (tid < NROWS) {
        idxbuf[0][tid] = tid;
        // build static triangle table: row i entries at 31i - i(i-1)/2
        int i = tid;
        int base = 31 * i - (i * (i - 1)) / 2;
        for (int j = i + 1; j < NROWS; j++)
            pairTab[base + (j - i - 1)] = (i << 8) | j;
    }

    // ---------- single-pass init: stream row i, owner captures, dist vs s<i ----------
    {
        const float4* src = (const float4*)xb;    // row 0
        #pragma unroll
        for (int q = 0; q < 4; q++) {
            float4 t = src[lane * 4 + q];
            m[4*q] = t.x; m[4*q+1] = t.y; m[4*q+2] = t.z; m[4*q+3] = t.w;
        }
    }
    #pragma unroll 1
    for (int i = 0; i < NROWS; i++) {
        if (i < NROWS - 1) {                      // prefetch row i+1
            const float4* src = (const float4*)(xb + (size_t)(i + 1) * CDIM);
            #pragma unroll
            for (int q = 0; q < 4; q++) {
                float4 t = src[lane * 4 + q];
                nxt[4*q] = t.x; nxt[4*q+1] = t.y; nxt[4*q+2] = t.z; nxt[4*q+3] = t.w;
            }
        }
        float accv[4];
        #pragma unroll
        for (int k = 0; k < 4; k++) {
            const int s = wid + (k << 3);         // strided slot, wave-uniform
            float acc0 = 0.0f, acc1 = 0.0f;
            if (s < i) {                          // wave-uniform
                #pragma unroll
                for (int e = 0; e < 8; e++) {
                    float d0 = m[e] - R[k][e];
                    float d1 = m[e + 8] - R[k][e + 8];
                    acc0 += d0 * d0;
                    acc1 += d1 * d1;
                }
            } else if (s == i) {                  // owner captures streamed row
                #pragma unroll
                for (int e = 0; e < 16; e++) R[k][e] = m[e];
            }
            accv[k] = acc0 + acc1;
        }
        float c = reduce4f(accv[0], accv[1], accv[2], accv[3], lane);
        int s_lane = wid + ((lane & 3) << 3);     // slot for this lane's sum
        if (lane < 4 && s_lane < i) { D[i][s_lane] = c; D[s_lane][i] = c; }

        if (i < NROWS - 1) {
            #pragma unroll
            for (int e = 0; e < 16; e++) m[e] = nxt[e];
        }
    }
    __syncthreads();

    // ---------- main merge loop: 3 barriers/step ----------
    int p = 0;
    #pragma unroll 1
    for (int step = 0; step < NSTEPS; step++) {
        const int n = NROWS - step;
        int* idx  = idxbuf[p];
        int* nidx = idxbuf[p ^ 1];
        const uint32_t M = 0xFFFFFFFFu / (uint32_t)n + 1u;  // exact for flat<2^27

        // --- argmin: one live-position pair per thread (static table) ---
        unsigned long long bk = ~0ull;
        if (tid < 496) {
            const int pr = pairTab[tid];
            const int i2 = pr >> 8, j2 = pr & 255;          // i2 < j2 < 32
            if (j2 < n) {                                   // both alive
                const int si = idx[i2], sj = idx[j2];
                uint32_t d2b = __float_as_uint(D[si][sj]);  // d2>=0: monotone bits
                bk = ((unsigned long long)d2b << 10) | (unsigned)(i2 * n + j2);
            }
        }
        #pragma unroll
        for (int off = 1; off < 64; off <<= 1) {
            unsigned long long ov = __shfl_xor(bk, off);
            bk = (ov < bk) ? ov : bk;
        }
        if (lane == 0) wp[wid] = bk;
        __syncthreads();                                   // B1

        // --- final reduce of 8 partials, redundant on every thread (uniform) ---
        bk = wp[0];
        #pragma unroll
        for (int w = 1; w < 8; w++) {
            unsigned long long ov = wp[w];
            bk = (ov < bk) ? ov : bk;
        }
        const int bp  = (int)(bk & 1023u);
        const int a   = (int)__umulhi((uint32_t)bp, M);
        const int bbj = bp - a * n;
        const int sa  = idx[a], sb = idx[bbj];
        const int deadSlot = (a == 1) ? idx[0] : sa;

        // --- conv partials by owner waves, from registers, float4-packed LDS ---
        #pragma unroll
        for (int k = 0; k < 4; k++) {
            const int s = bs[k];                           // register, wave-uniform
            if (s == sa || s == sb) {
                float hl = __shfl_up(R[k][15], 1);  if (lane == 0)  hl = 0.0f;
                float hr = __shfl_down(R[k][0], 1); if (lane == 63) hr = 0.0f;
                float4* dst = (s == sa) ? mA4 : mB4;
                const float c0 = (s == sa) ? w00 : w10;
                const float c1 = (s == sa) ? w01 : w11;
                const float c2 = (s == sa) ? w02 : w12;
                #pragma unroll
                for (int q = 0; q < 4; q++) {
                    float vv[4];
                    #pragma unroll
                    for (int j = 0; j < 4; j++) {
                        const int e = 4 * q + j;
                        float xm1 = (e == 0)  ? hl : R[k][e - 1];
                        float xp1 = (e == 15) ? hr : R[k][e + 1];
                        vv[j] = c0 * xm1 + c1 * R[k][e] + c2 * xp1;
                    }
                    dst[q * 64 + lane] = make_float4(vv[0], vv[1], vv[2], vv[3]);
                }
            }
        }
        // --- bookkeeping: next logical order (merged keeps slot id sb) ---
        if (tid == 0) nidx[0] = sb;
        if (tid >= 1 && tid < n - 1) {
            int kk = tid + 1;
            int src = (kk == bbj) ? 1 : ((kk == a) ? 0 : kk);
            nidx[tid] = idx[src];
        }
        __syncthreads();                                   // B2

        // --- finalize m: 4x ds_read_b128 per array, conflict-free ---
        #pragma unroll
        for (int q = 0; q < 4; q++) {
            float4 va = mA4[q * 64 + lane];
            float4 vb = mB4[q * 64 + lane];
            float v0 = cb + va.x + vb.x;
            float v1 = cb + va.y + vb.y;
            float v2 = cb + va.z + vb.z;
            float v3 = cb + va.w + vb.w;
            m[4*q+0] = v0 > 0.0f ? v0 : 0.0f;
            m[4*q+1] = v1 > 0.0f ? v1 : 0.0f;
            m[4*q+2] = v2 > 0.0f ? v2 : 0.0f;
            m[4*q+3] = v3 > 0.0f ? v3 : 0.0f;
        }
        // owner(sb): bank <- m; owner(deadSlot): kill bank; dists vs live banks
        float accv[4]; int slv[4];
        #pragma unroll
        for (int k = 0; k < 4; k++) {
            int s = bs[k];
            if (s == sb) {                                 // wave-uniform
                #pragma unroll
                for (int e = 0; e < 16; e++) R[k][e] = m[e];
            }
            if (s == deadSlot) {                           // wave-uniform
                bs[k] = -1;
                s = -1;
            }
            const int live = (s >= 0 && s != sb) ? s : -1;
            slv[k] = live;
            float acc0 = 0.0f, acc1 = 0.0f;
            if (live >= 0) {                               // wave-uniform
                #pragma unroll
                for (int e = 0; e < 8; e++) {
                    float d0 = m[e] - R[k][e];
                    float d1 = m[e + 8] - R[k][e + 8];
                    acc0 += d0 * d0;
                    acc1 += d1 * d1;
                }
            }
            accv[k] = acc0 + acc1;
        }
        // joint reduce: lane l holds sum for bank (l&3)
        float c = reduce4f(accv[0], accv[1], accv[2], accv[3], lane);
        int s_lane = slv[0];
        s_lane = ((lane & 3) == 1) ? slv[1] : s_lane;
        s_lane = ((lane & 3) == 2) ? slv[2] : s_lane;
        s_lane = ((lane & 3) == 3) ? slv[3] : s_lane;
        if (lane < 4 && s_lane >= 0) {
            D[sb][s_lane] = c; D[s_lane][sb] = c;
        }
        __syncthreads();                                   // B3
        p ^= 1;
    }

    // final merged row is in m (all waves); wave 0 writes it
    if (wid == 0) {
        float4* od = (float4*)(out + (size_t)b * CDIM);
        #pragma unroll
        for (int q = 0; q < 4; q++)
            od[lane * 4 + q] = make_float4(m[4*q], m[4*q+1], m[4*q+2], m[4*q+3]);
    }
}

extern "C" void kernel_launch(void* const* d_in, const int* in_sizes, int n_in,
                              void* d_out, int out_size, void* d_ws, size_t ws_size,
                              hipStream_t stream) {
    const float* x  = (const float*)d_in[0]; // fp32 (512,32,1024)
    const float* w  = (const float*)d_in[1]; // fp32 (1,2,3)
    const float* cb = (const float*)d_in[2]; // fp32 (1,)
    float* out = (float*)d_out;              // fp32 (512,1024)
    (void)d_ws; (void)ws_size; (void)in_sizes; (void)n_in; (void)out_size;

    hipLaunchKernelGGL(merge_tree_kernel, dim3(BATCH), dim3(BDIM), 0, stream,
                       x, w, cb, out);
}